// Round 1
// baseline (3870.782 us; speedup 1.0000x reference)
//
#include <hip/hip_runtime.h>
#include <cstdint>

// DA_RNN particle filter, B=128 T=32 H=256 K=32.
// RNG: JAX threefry2x32, **partitionable** scheme (jax >= 0.5 default):
//   fold_in(key,t)     = block(key, (0,t))
//   split -> k_i       = block(key, (0,i))  (both outputs form the child key)
//   random_bits[i]     = o0^o1 of block(key, (0,i))
// If absmax comes back ~0.2 (noise-level), switch to the pre-0.5 scheme.

#define Bn 128
#define Tn 32
#define Hn 256
#define Kn 32

__host__ __device__ inline void tf2x32(uint32_t k0, uint32_t k1, uint32_t x0, uint32_t x1,
                                       uint32_t &o0, uint32_t &o1) {
  uint32_t ks2 = k0 ^ k1 ^ 0x1BD11BDAu;
  x0 += k0; x1 += k1;
#define TFR(r) { x0 += x1; x1 = (x1 << r) | (x1 >> (32 - r)); x1 ^= x0; }
  TFR(13) TFR(15) TFR(26) TFR(6)
  x0 += k1;  x1 += ks2 + 1u;
  TFR(17) TFR(29) TFR(16) TFR(24)
  x0 += ks2; x1 += k0 + 2u;
  TFR(13) TFR(15) TFR(26) TFR(6)
  x0 += k0;  x1 += k1 + 3u;
  TFR(17) TFR(29) TFR(16) TFR(24)
  x0 += k1;  x1 += ks2 + 4u;
  TFR(13) TFR(15) TFR(26) TFR(6)
  x0 += ks2; x1 += k0 + 5u;
#undef TFR
  o0 = x0; o1 = x1;
}

// XLA ErfInv (Giles single-precision polynomial) — must match XLA, not HIP erfinvf.
__device__ __forceinline__ float erfinv_xla(float x) {
  float w = -log1pf(-x * x);
  float p;
  if (w < 5.0f) {
    w = w - 2.5f;
    p = 2.81022636e-08f;
    p = fmaf(p, w, 3.43273939e-07f);
    p = fmaf(p, w, -3.5233877e-06f);
    p = fmaf(p, w, -4.39150654e-06f);
    p = fmaf(p, w, 0.00021858087f);
    p = fmaf(p, w, -0.00125372503f);
    p = fmaf(p, w, -0.00417768164f);
    p = fmaf(p, w, 0.246640727f);
    p = fmaf(p, w, 1.50140941f);
  } else {
    w = sqrtf(w) - 3.0f;
    p = -0.000200214257f;
    p = fmaf(p, w, 0.000100950558f);
    p = fmaf(p, w, 0.00134934322f);
    p = fmaf(p, w, -0.00367342844f);
    p = fmaf(p, w, 0.00573950773f);
    p = fmaf(p, w, -0.0076224613f);
    p = fmaf(p, w, 0.00943887047f);
    p = fmaf(p, w, 1.00167406f);
    p = fmaf(p, w, 2.83297682f);
  }
  return p * x;
}

__device__ __forceinline__ float sigmoid_xla(float x) {
  // XLA LogisticExpander form
  return 0.5f + 0.5f * tanhf(0.5f * x);
}

__device__ __forceinline__ float u01_from_bits(uint32_t bits) {
  return __uint_as_float((bits >> 9) | 0x3F800000u) - 1.0f;
}

__device__ __forceinline__ float normal_from_idx(uint32_t ka, uint32_t kb, uint32_t idx) {
  uint32_t o0, o1; tf2x32(ka, kb, 0u, idx, o0, o1);
  float f = u01_from_bits(o0 ^ o1);
  const float LO = __uint_as_float(0xBF7FFFFFu);     // nextafter(-1,0)
  float u = fmaxf(LO, f * 2.0f + LO);                // (1 - LO) rounds to exactly 2.0f
  return __uint_as_float(0x3FB504F3u) * erfinv_xla(u); // sqrt(2) * erfinv(u)
}

__device__ __forceinline__ float gumbel_from_idx(uint32_t ka, uint32_t kb, uint32_t idx) {
  uint32_t o0, o1; tf2x32(ka, kb, 0u, idx, o0, o1);
  float f = u01_from_bits(o0 ^ o1);
  const float TINY = __uint_as_float(0x00800000u);   // finfo(f32).tiny
  float u = fmaxf(TINY, f + TINY);                   // (1 - tiny) rounds to 1.0f
  return -logf(-logf(u));
}

// ---------------- precompute kernels ----------------

// W1hT/W1cT/W1eT: [j][ho] transposes of attn_W1 column blocks.
// WhhT: gate-interleaved [j][h*4+q] <- W_hh[(q*256+h)*256 + j]  (float4-load friendly)
__global__ void darnn_p0(const float* __restrict__ W1, const float* __restrict__ Whh,
                         float* __restrict__ W1hT, float* __restrict__ W1cT,
                         float* __restrict__ W1eT, float* __restrict__ WhhT) {
  int bid = blockIdx.x, tid = threadIdx.x;
  if (bid < 768) {
    int part = bid >> 8, j = bid & 255;
    float v = W1[tid * 768 + part * 256 + j];
    float* dst = (part == 0) ? W1hT : (part == 1) ? W1cT : W1eT;
    dst[j * 256 + tid] = v;
  } else {
    int j = bid - 768;
    for (int idx = tid; idx < 1024; idx += 256) {
      int h = idx >> 2, q = idx & 3;
      WhhT[j * 1024 + idx] = Whh[(q * 256 + h) * 256 + j];
    }
  }
}

// encW1[b,t,ho] = b1[ho] + sum_j enc[b,t,j]*W1[ho, 512+j]   (scan-invariant, hoisted)
__global__ void darnn_p1(const float* __restrict__ enc, const float* __restrict__ W1eT,
                         const float* __restrict__ b1, float* __restrict__ encW1) {
  int bt = blockIdx.x, tid = threadIdx.x;
  __shared__ float se[256];
  se[tid] = enc[bt * 256 + tid];
  __syncthreads();
  float acc = 0.f;
  for (int j = 0; j < 256; ++j) acc = fmaf(se[j], W1eT[j * 256 + tid], acc);
  encW1[bt * 256 + tid] = acc + b1[tid];
}

// ---------------- per-step kernels ----------------

// particle means + (hm,cm) @ W1 parts
__global__ void darnn_k12(const float* __restrict__ hid, const float* __restrict__ cel,
                          const float* __restrict__ W1hT, const float* __restrict__ W1cT,
                          float* __restrict__ hm_g, float* __restrict__ hmc_g) {
  int b = blockIdx.x, tid = threadIdx.x;
  __shared__ float sh[256], sc[256];
  float s1 = 0.f, s2 = 0.f;
  for (int k = 0; k < 32; ++k) {
    s1 += hid[(k * 128 + b) * 256 + tid];
    s2 += cel[(k * 128 + b) * 256 + tid];
  }
  s1 *= 0.03125f; s2 *= 0.03125f;
  hm_g[b * 256 + tid] = s1;
  sh[tid] = s1; sc[tid] = s2;
  __syncthreads();
  float acc = 0.f;
  for (int j = 0; j < 256; ++j) {
    acc = fmaf(sh[j], W1hT[j * 256 + tid], acc);
    acc = fmaf(sc[j], W1cT[j * 256 + tid], acc);
  }
  hmc_g[b * 256 + tid] = acc;
}

// attention scores -> softmax -> context -> y_tilde
__global__ void darnn_k3(const float* __restrict__ encW1, const float* __restrict__ hmc_g,
                         const float* __restrict__ enc, const float* __restrict__ W2,
                         const float* __restrict__ b2p, const float* __restrict__ fcW,
                         const float* __restrict__ fcbp, const float* __restrict__ y_prev,
                         int t, float* __restrict__ ctx_g, float* __restrict__ ytl) {
  int b = blockIdx.x, tid = threadIdx.x, lane = tid & 63, wv = tid >> 6;
  __shared__ float ssc[32], sbeta[32], red[256];
  for (int tt = wv * 8; tt < wv * 8 + 8; ++tt) {
    float p = 0.f;
    for (int h = lane; h < 256; h += 64)
      p += tanhf(encW1[(b * 32 + tt) * 256 + h] + hmc_g[b * 256 + h]) * W2[h];
    for (int off = 32; off; off >>= 1) p += __shfl_down(p, off);
    if (lane == 0) ssc[tt] = p + b2p[0];
  }
  __syncthreads();
  if (tid == 0) {
    float m = ssc[0];
    for (int k = 1; k < 32; ++k) m = fmaxf(m, ssc[k]);
    float s = 0.f;
    for (int k = 0; k < 32; ++k) { float e = expf(ssc[k] - m); sbeta[k] = e; s += e; }
    for (int k = 0; k < 32; ++k) sbeta[k] /= s;
  }
  __syncthreads();
  float c = 0.f;
  for (int tt = 0; tt < 32; ++tt) c = fmaf(sbeta[tt], enc[(b * 32 + tt) * 256 + tid], c);
  ctx_g[b * 256 + tid] = c;
  red[tid] = c * fcW[tid];
  __syncthreads();
  if (tid == 0) {
    float s = 0.f;
    for (int j = 0; j < 256; ++j) s += red[j];
    s += y_prev[b * 32 + t] * fcW[256];
    ytl[b] = s + fcbp[0];
  }
}

// var head -> std = softplus(var)
__global__ void darnn_k4(const float* __restrict__ hm_g, const float* __restrict__ ytl,
                         const float* __restrict__ varW, const float* __restrict__ varb,
                         float* __restrict__ stdv) {
  int b = blockIdx.x, tid = threadIdx.x;
  __shared__ float sh[256];
  sh[tid] = hm_g[b * 256 + tid];
  __syncthreads();
  const float* wr = varW + tid * 257;
  float v = ytl[b] * wr[0];
  for (int j = 0; j < 256; ++j) v = fmaf(sh[j], wr[1 + j], v);
  v += varb[tid];
  // jnp.logaddexp(v, 0)
  stdv[b * 256 + tid] = fmaxf(v, 0.f) + log1pf(expf(-fabsf(v)));
}

// LSTM gates GEMM + cell update + reparam noise + proj/pdot row reductions
__launch_bounds__(256)
__global__ void darnn_k5(const float* __restrict__ hid, const float* __restrict__ cel,
                         const float* __restrict__ WhhT, const float* __restrict__ Wih,
                         const float* __restrict__ bih, const float* __restrict__ bhh,
                         const float* __restrict__ ytl, const float* __restrict__ stdv,
                         const float* __restrict__ decW, const float* __restrict__ decbp,
                         const float* __restrict__ pdfW,
                         uint32_t k1a, uint32_t k1b,
                         float* __restrict__ hnew, float* __restrict__ cnew,
                         float* __restrict__ proj, float* __restrict__ pdot) {
  int r0 = blockIdx.x * 8, tid = threadIdx.x;
  __shared__ float sh[8 * 256];
  __shared__ float sred[4];
  for (int r = 0; r < 8; ++r) sh[r * 256 + tid] = hid[(r0 + r) * 256 + tid];
  __syncthreads();
  float ai[8], af[8], ag[8], ao[8];
#pragma unroll
  for (int r = 0; r < 8; ++r) { ai[r] = af[r] = ag[r] = ao[r] = 0.f; }
  const float4* wp = (const float4*)WhhT + tid;   // [j*256 + tid] float4s
  for (int j = 0; j < 256; ++j) {
    float4 w4 = wp[j * 256];
#pragma unroll
    for (int r = 0; r < 8; ++r) {
      float hj = sh[r * 256 + j];
      ai[r] = fmaf(hj, w4.x, ai[r]);
      af[r] = fmaf(hj, w4.y, af[r]);
      ag[r] = fmaf(hj, w4.z, ag[r]);
      ao[r] = fmaf(hj, w4.w, ao[r]);
    }
  }
  float bI = bih[tid], bF = bih[256 + tid], bG = bih[512 + tid], bO = bih[768 + tid];
  float dI = bhh[tid], dF = bhh[256 + tid], dG = bhh[512 + tid], dO = bhh[768 + tid];
  float wI = Wih[tid], wF = Wih[256 + tid], wG = Wih[512 + tid], wO = Wih[768 + tid];
  float dw = decW[tid], pw = pdfW[tid];
  float hnv[8];
#pragma unroll
  for (int r = 0; r < 8; ++r) {
    int row = r0 + r, b = row & 127;
    float xb = ytl[b];
    float pi = ((xb * wI + bI) + ai[r]) + dI;
    float pf = ((xb * wF + bF) + af[r]) + dF;
    float pg = ((xb * wG + bG) + ag[r]) + dG;
    float po = ((xb * wO + bO) + ao[r]) + dO;
    float c_old = cel[row * 256 + tid];
    float cn = sigmoid_xla(pf) * c_old + sigmoid_xla(pi) * tanhf(pg);
    float hn = sigmoid_xla(po) * tanhf(cn);
    float eps = normal_from_idx(k1a, k1b, (uint32_t)(row * 256 + tid));
    hn = hn + eps * stdv[b * 256 + tid];
    cnew[row * 256 + tid] = cn;
    hnew[row * 256 + tid] = hn;
    hnv[r] = hn;
  }
  int lane = tid & 63, wvi = tid >> 6;
  for (int r = 0; r < 8; ++r) {
    float v = hnv[r] * dw;
    for (int off = 32; off; off >>= 1) v += __shfl_down(v, off);
    if (lane == 0) sred[wvi] = v;
    __syncthreads();
    if (tid == 0) proj[r0 + r] = ((sred[0] + sred[1]) + (sred[2] + sred[3])) + decbp[0];
    __syncthreads();
    v = hnv[r] * pw;
    for (int off = 32; off; off >>= 1) v += __shfl_down(v, off);
    if (lane == 0) sred[wvi] = v;
    __syncthreads();
    if (tid == 0) pdot[r0 + r] = (sred[0] + sred[1]) + (sred[2] + sred[3]);
    __syncthreads();
  }
}

// stable-argsort ranks per batch + particle weights
__global__ void darnn_f1(const float* __restrict__ proj, const float* __restrict__ pdot,
                         const float* __restrict__ ytl, const float* __restrict__ pdfW,
                         const float* __restrict__ pdfbp,
                         int* __restrict__ srck, float* __restrict__ wbuf) {
  int b = blockIdx.x, tid = threadIdx.x;
  __shared__ float pp[32], pd[32];
  if (tid < 32) { pp[tid] = proj[tid * 128 + b]; pd[tid] = pdot[tid * 128 + b]; }
  __syncthreads();
  if (tid < 32) {
    float p = pp[tid];
    int rank = 0;
    for (int kk = 0; kk < 32; ++kk) {
      float q = pp[kk];
      rank += (q < p) || (q == p && kk < tid);
    }
    srck[rank * 128 + b] = tid;
    float wv = expf((pd[tid] + ytl[b] * pdfW[256]) + pdfbp[0]);
    wbuf[rank * 128 + b] = wv;
  }
}

// denominators over the torch-style (B,K) reshape (flat runs of 32)
__global__ void darnn_f2(const float* __restrict__ wbuf, float* __restrict__ denom) {
  int bp = blockIdx.x * 64 + threadIdx.x;
  if (bp < 128) {
    float s = 0.f;
    for (int k = 0; k < 32; ++k) s += wbuf[bp * 32 + k];
    denom[bp] = s;
  }
}

// Gumbel-argmax categorical + gather of (h_sorted, unsorted c_new)
__global__ void darnn_f3(const float* __restrict__ hnew, const float* __restrict__ cnew,
                         const float* __restrict__ wbuf, const float* __restrict__ denom,
                         const int* __restrict__ srck, uint32_t k2a, uint32_t k2b,
                         float* __restrict__ hid, float* __restrict__ cel) {
  int r2 = blockIdx.x, tid = threadIdx.x;  // r2 = k_out*128 + b
  int b = r2 & 127;
  __shared__ float vals[32];
  if (tid < 32) {
    int rfl = tid * 128 + b;
    float logit = logf(wbuf[rfl] / denom[rfl >> 5]);
    float g = gumbel_from_idx(k2a, k2b, (uint32_t)(r2 * 32 + tid));
    vals[tid] = g + logit;
  }
  __syncthreads();
  float best = vals[0]; int sv = 0;
  for (int k = 1; k < 32; ++k) { float v = vals[k]; if (v > best) { best = v; sv = k; } }
  int srh = srck[sv * 128 + b] * 128 + b;  // h_sorted[samp*B+b] = h_new[srck[samp]*B+b]
  int src = sv * 128 + b;                  // c_new indexed by flat2 directly (unsorted)
  const float4* hs = (const float4*)(hnew + (size_t)srh * 256);
  const float4* cs = (const float4*)(cnew + (size_t)src * 256);
  float4* hd = (float4*)(hid + (size_t)r2 * 256);
  float4* cd = (float4*)(cel + (size_t)r2 * 256);
  hd[tid] = hs[tid];
  cd[tid] = cs[tid];
}

__global__ void darnn_k1f(const float* __restrict__ hid, float* __restrict__ hm_g) {
  int b = blockIdx.x, tid = threadIdx.x;
  float s = 0.f;
  for (int k = 0; k < 32; ++k) s += hid[(k * 128 + b) * 256 + tid];
  hm_g[b * 256 + tid] = s * 0.03125f;
}

__global__ void darnn_out(const float* __restrict__ hm_g, const float* __restrict__ ctx_g,
                          const float* __restrict__ decW, const float* __restrict__ decbp,
                          const float* __restrict__ encW, const float* __restrict__ encbp,
                          float* __restrict__ out) {
  int b = blockIdx.x, tid = threadIdx.x, lane = tid & 63, wvi = tid >> 6;
  __shared__ float sred[8];
  float v1 = hm_g[b * 256 + tid] * decW[tid];
  float v2 = ctx_g[b * 256 + tid] * encW[tid];
  for (int off = 32; off; off >>= 1) { v1 += __shfl_down(v1, off); v2 += __shfl_down(v2, off); }
  if (lane == 0) { sred[wvi] = v1; sred[4 + wvi] = v2; }
  __syncthreads();
  if (tid == 0) {
    float d1 = (sred[0] + sred[1]) + (sred[2] + sred[3]);
    float d2 = (sred[4] + sred[5]) + (sred[6] + sred[7]);
    out[b] = ((d1 + decbp[0]) + d2) + encbp[0];
  }
}

extern "C" void kernel_launch(void* const* d_in, const int* in_sizes, int n_in,
                              void* d_out, int out_size, void* d_ws, size_t ws_size,
                              hipStream_t stream) {
  const float* enc   = (const float*)d_in[0];
  const float* yprev = (const float*)d_in[1];
  const float* W1    = (const float*)d_in[2];
  const float* b1    = (const float*)d_in[3];
  const float* W2    = (const float*)d_in[4];
  const float* b2    = (const float*)d_in[5];
  const float* fcW   = (const float*)d_in[6];
  const float* fcb   = (const float*)d_in[7];
  const float* varW  = (const float*)d_in[8];
  const float* varb  = (const float*)d_in[9];
  const float* Wih   = (const float*)d_in[10];
  const float* Whh   = (const float*)d_in[11];
  const float* bih   = (const float*)d_in[12];
  const float* bhh   = (const float*)d_in[13];
  const float* decW  = (const float*)d_in[14];
  const float* decb  = (const float*)d_in[15];
  const float* pdfW  = (const float*)d_in[16];
  const float* pdfb  = (const float*)d_in[17];
  const float* encWo = (const float*)d_in[18];
  const float* encbo = (const float*)d_in[19];

  float* ws = (float*)d_ws;
  size_t o = 0;
  float* encW1 = ws + o; o += (size_t)Bn * Tn * Hn;   // 1,048,576
  float* W1hT  = ws + o; o += (size_t)Hn * Hn;        // 65,536
  float* W1cT  = ws + o; o += (size_t)Hn * Hn;
  float* W1eT  = ws + o; o += (size_t)Hn * Hn;
  float* WhhT  = ws + o; o += (size_t)Hn * 4 * Hn;    // 262,144
  float* hid   = ws + o; o += (size_t)Kn * Bn * Hn;   // 1,048,576
  float* cel   = ws + o; o += (size_t)Kn * Bn * Hn;
  float* hnew  = ws + o; o += (size_t)Kn * Bn * Hn;
  float* cnew  = ws + o; o += (size_t)Kn * Bn * Hn;
  float* hm    = ws + o; o += (size_t)Bn * Hn;
  float* ctx   = ws + o; o += (size_t)Bn * Hn;
  float* stdv  = ws + o; o += (size_t)Bn * Hn;
  float* hmc   = ws + o; o += (size_t)Bn * Hn;
  float* ytl   = ws + o; o += 128;
  float* proj  = ws + o; o += 4096;
  float* pdot  = ws + o; o += 4096;
  float* wbuf  = ws + o; o += 4096;
  float* denom = ws + o; o += 128;
  int*   srck  = (int*)(ws + o); o += 4096;
  if (ws_size < o * sizeof(float)) return;  // workspace too small: bail (bench will flag)

  // initial LSTM state = zeros (ws is poisoned 0xAA before every call)
  hipMemsetAsync(hid, 0, 2ull * Kn * Bn * Hn * sizeof(float), stream);

  darnn_p0<<<1024, 256, 0, stream>>>(W1, Whh, W1hT, W1cT, W1eT, WhhT);
  darnn_p1<<<Bn * Tn, 256, 0, stream>>>(enc, W1eT, b1, encW1);

  for (int t = 0; t < Tn; ++t) {
    // host-side key chain: fold_in(key(42), t) then partitionable split
    uint32_t f0, f1, k1a, k1b, k2a, k2b;
    tf2x32(0u, 42u, 0u, (uint32_t)t, f0, f1);
    tf2x32(f0, f1, 0u, 0u, k1a, k1b);
    tf2x32(f0, f1, 0u, 1u, k2a, k2b);

    darnn_k12<<<Bn, 256, 0, stream>>>(hid, cel, W1hT, W1cT, hm, hmc);
    darnn_k3 <<<Bn, 256, 0, stream>>>(encW1, hmc, enc, W2, b2, fcW, fcb, yprev, t, ctx, ytl);
    darnn_k4 <<<Bn, 256, 0, stream>>>(hm, ytl, varW, varb, stdv);
    darnn_k5 <<<Kn * Bn / 8, 256, 0, stream>>>(hid, cel, WhhT, Wih, bih, bhh, ytl, stdv,
                                               decW, decb, pdfW, k1a, k1b,
                                               hnew, cnew, proj, pdot);
    darnn_f1 <<<Bn, 64, 0, stream>>>(proj, pdot, ytl, pdfW, pdfb, srck, wbuf);
    darnn_f2 <<<2, 64, 0, stream>>>(wbuf, denom);
    darnn_f3 <<<Kn * Bn, 64, 0, stream>>>(hnew, cnew, wbuf, denom, srck, k2a, k2b, hid, cel);
  }

  darnn_k1f<<<Bn, 256, 0, stream>>>(hid, hm);
  darnn_out<<<Bn, 256, 0, stream>>>(hm, ctx, decW, decb, encWo, encbo, (float*)d_out);
}